// Round 1
// baseline (554.110 us; speedup 1.0000x reference)
//
#include <hip/hip_runtime.h>
#include <hip/hip_bf16.h>

#define NASP 5
#define H1 10
#define SEQ 500
#define EMB 300
#define NCOL 52          // padded 5*10 -> 52 (cols 50,51 are zero)
#define DSTRIDE 36       // doc LDS tile row stride in floats (144 B: b128-aligned, conflict-free)
#define THREADS 512
#define DOC_LDS (SEQ * DSTRIDE)   // 18000 floats

__global__ __launch_bounds__(THREADS, 4)
void arl_fused(const float* __restrict__ doc,
               const float* __restrict__ Wg,     // [5][300][10]
               const float* __restrict__ embG,   // [5][30]
               float* __restrict__ out,
               int B) {
    __shared__ float SB[DOC_LDS + 32 * NCOL];    // 19664 floats = 78.7 KB

    const int tid  = threadIdx.x;
    const int b    = blockIdx.x;
    const int s    = tid;
    const bool active = (s < SEQ);
    const int lane = tid & 63;
    const int wave = tid >> 6;

    const float* docB = doc + (size_t)b * (SEQ * EMB);
    float* Wt = &SB[DOC_LDS];

    float acc[NCOL];
    #pragma unroll
    for (int j = 0; j < NCOL; ++j) acc[j] = 0.f;

    // ---------------- phase 1: proj = doc x W, proj kept in registers ----------------
    for (int chunk = 0; chunk < 10; ++chunk) {
        const int e0 = chunk * 32;
        const int ec = (chunk < 9) ? 32 : 12;

        // stage doc tile [500][ec] -> SB rows of stride 36 (float4 coalesced)
        if (ec == 32) {
            for (int q = tid; q < SEQ * 8; q += THREADS) {
                int srow = q >> 3, c4 = q & 7;
                float4 v = *reinterpret_cast<const float4*>(docB + srow * EMB + e0 + (c4 << 2));
                *reinterpret_cast<float4*>(&SB[srow * DSTRIDE + (c4 << 2)]) = v;
            }
        } else {
            for (int q = tid; q < SEQ * 3; q += THREADS) {
                int srow = q / 3, c4 = q - srow * 3;
                float4 v = *reinterpret_cast<const float4*>(docB + srow * EMB + e0 + (c4 << 2));
                *reinterpret_cast<float4*>(&SB[srow * DSTRIDE + (c4 << 2)]) = v;
            }
        }
        // stage W tile [ec][52], cols 50,51 zeroed
        for (int q = tid; q < NCOL * 32; q += THREADS) {   // always fill 32 rows (stale rows unread when ec=12)
            int erow = q / NCOL, c = q - erow * NCOL;
            float val = 0.f;
            if (c < 50 && erow < ec) {
                int a = c / 10, h = c - 10 * a;
                val = Wg[a * (EMB * H1) + (e0 + erow) * H1 + h];
            }
            if (erow < ec) Wt[erow * NCOL + c] = val;
        }
        __syncthreads();

        if (active) {
            const int ne4 = ec >> 2;
            for (int e4 = 0; e4 < ne4; ++e4) {
                float4 d = *reinterpret_cast<const float4*>(&SB[s * DSTRIDE + (e4 << 2)]);
                const float* wb = &Wt[(e4 << 2) * NCOL];
                #pragma unroll
                for (int j4 = 0; j4 < 13; ++j4) {
                    float4 w0 = *reinterpret_cast<const float4*>(&wb[j4 * 4]);
                    float4 w1 = *reinterpret_cast<const float4*>(&wb[NCOL + j4 * 4]);
                    float4 w2 = *reinterpret_cast<const float4*>(&wb[2 * NCOL + j4 * 4]);
                    float4 w3 = *reinterpret_cast<const float4*>(&wb[3 * NCOL + j4 * 4]);
                    const int c = j4 * 4;
                    acc[c+0] = fmaf(d.x, w0.x, acc[c+0]);
                    acc[c+0] = fmaf(d.y, w1.x, acc[c+0]);
                    acc[c+0] = fmaf(d.z, w2.x, acc[c+0]);
                    acc[c+0] = fmaf(d.w, w3.x, acc[c+0]);
                    acc[c+1] = fmaf(d.x, w0.y, acc[c+1]);
                    acc[c+1] = fmaf(d.y, w1.y, acc[c+1]);
                    acc[c+1] = fmaf(d.z, w2.y, acc[c+1]);
                    acc[c+1] = fmaf(d.w, w3.y, acc[c+1]);
                    acc[c+2] = fmaf(d.x, w0.z, acc[c+2]);
                    acc[c+2] = fmaf(d.y, w1.z, acc[c+2]);
                    acc[c+2] = fmaf(d.z, w2.z, acc[c+2]);
                    acc[c+2] = fmaf(d.w, w3.z, acc[c+2]);
                    acc[c+3] = fmaf(d.x, w0.w, acc[c+3]);
                    acc[c+3] = fmaf(d.y, w1.w, acc[c+3]);
                    acc[c+3] = fmaf(d.z, w2.w, acc[c+3]);
                    acc[c+3] = fmaf(d.w, w3.w, acc[c+3]);
                }
            }
        }
        __syncthreads();
    }

    // ---------------- phase 2: scores, softmax, pooling (overlay dead doc LDS) -------
    float* embS  = &SB[0];      // 150 floats
    float* Ubuf  = &SB[160];    // 5 * 513
    float* W3buf = &SB[2725];   // 5 * 501
    float* red   = &SB[5232];   // 8 * 52 (reused: 8*5 for softmax reductions)

    if (tid < NASP * 3 * H1) embS[tid] = embG[tid];
    __syncthreads();

    // u/v/w partial dots against the 3 context slots of the aspect embedding
    float uu[NASP], vv[NASP], ww[NASP];
    #pragma unroll
    for (int a = 0; a < NASP; ++a) {
        float su = 0.f, sv = 0.f, sw = 0.f;
        #pragma unroll
        for (int h = 0; h < H1; ++h) {
            float pj = acc[a * 10 + h];
            su = fmaf(pj, embS[a * 30 + h],       su);
            sv = fmaf(pj, embS[a * 30 + 10 + h],  sv);
            sw = fmaf(pj, embS[a * 30 + 20 + h],  sw);
        }
        uu[a] = su; vv[a] = sv; ww[a] = sw;
    }
    if (active) {
        #pragma unroll
        for (int a = 0; a < NASP; ++a) {
            Ubuf[a * 513 + s + 1] = uu[a];   // read back at [s] -> u[s-1]
            W3buf[a * 501 + s]    = ww[a];   // read back at [s+1] -> w[s+1]
        }
    }
    if (tid == 0) {
        #pragma unroll
        for (int a = 0; a < NASP; ++a) { Ubuf[a * 513] = 0.f; W3buf[a * 501 + 500] = 0.f; }
    }
    __syncthreads();

    float sc[NASP];
    #pragma unroll
    for (int a = 0; a < NASP; ++a)
        sc[a] = active ? (Ubuf[a * 513 + s] + vv[a] + W3buf[a * 501 + s + 1]) : -1e30f;

    // block-wide max per aspect
    float m[NASP];
    #pragma unroll
    for (int a = 0; a < NASP; ++a) {
        float x = sc[a];
        #pragma unroll
        for (int off = 32; off > 0; off >>= 1) x = fmaxf(x, __shfl_xor(x, off));
        if (lane == 0) red[wave * NASP + a] = x;
    }
    __syncthreads();
    #pragma unroll
    for (int a = 0; a < NASP; ++a) {
        float mm = red[a];
        #pragma unroll
        for (int w2 = 1; w2 < 8; ++w2) mm = fmaxf(mm, red[w2 * NASP + a]);
        m[a] = mm;
    }
    __syncthreads();

    // exp + block-wide sum per aspect
    float p[NASP];
    #pragma unroll
    for (int a = 0; a < NASP; ++a) {
        float x = active ? __expf(sc[a] - m[a]) : 0.f;
        p[a] = x;
        float t = x;
        #pragma unroll
        for (int off = 32; off > 0; off >>= 1) t += __shfl_xor(t, off);
        if (lane == 0) red[wave * NASP + a] = t;
    }
    __syncthreads();
    float attnv[NASP];
    #pragma unroll
    for (int a = 0; a < NASP; ++a) {
        float ssum = 0.f;
        #pragma unroll
        for (int w2 = 0; w2 < 8; ++w2) ssum += red[w2 * NASP + a];
        attnv[a] = p[a] / ssum;
    }

    // write attention output [B][5][500]
    if (active) {
        #pragma unroll
        for (int a = 0; a < NASP; ++a)
            out[((size_t)b * NASP + a) * SEQ + s] = attnv[a];
    }
    __syncthreads();   // red about to be reused for pooling

    // rep[a][h] = sum_s proj * attn  (block reduction of 50 values)
    #pragma unroll
    for (int j = 0; j < 50; ++j) {
        float x = acc[j] * attnv[j / 10];
        #pragma unroll
        for (int off = 32; off > 0; off >>= 1) x += __shfl_xor(x, off);
        if (lane == 0) red[wave * 52 + j] = x;
    }
    __syncthreads();
    if (tid < 50) {
        float ssum = 0.f;
        #pragma unroll
        for (int w2 = 0; w2 < 8; ++w2) ssum += red[w2 * 52 + tid];
        out[(size_t)B * NASP * SEQ + (size_t)b * 50 + tid] = ssum;
    }
}

extern "C" void kernel_launch(void* const* d_in, const int* in_sizes, int n_in,
                              void* d_out, int out_size, void* d_ws, size_t ws_size,
                              hipStream_t stream) {
    const float* doc = (const float*)d_in[0];
    const float* Wg  = (const float*)d_in[1];
    const float* emb = (const float*)d_in[2];
    float* out = (float*)d_out;
    const int B = in_sizes[0] / (SEQ * EMB);   // 1024
    arl_fused<<<dim3(B), dim3(THREADS), 0, stream>>>(doc, Wg, emb, out, B);
}